// Round 12
// baseline (184.940 us; speedup 1.0000x reference)
//
#include <hip/hip_runtime.h>
#include <hip/hip_bf16.h>

// Problem constants
#define B_   16
#define C_   64
#define G_   256
#define P_   4096
#define W_   1024
#define H_   256
#define WQ_  256
#define M_   (B_ * P_)   // 65536 flattened (b,p) rows

typedef __attribute__((ext_vector_type(8))) _Float16 f16x8;  // MFMA A/B frag (4 VGPRs)
typedef __attribute__((ext_vector_type(4))) float    f32x4;  // MFMA C/D frag

__device__ __forceinline__ float h2f(ushort u) {
    union { ushort u; _Float16 h; } cv; cv.u = u;
    return (float)cv.h;
}

// async global->LDS, 16B per lane (dest = wave-uniform base + lane*16)
#define GLOAD16(gsrc, ldst)                                                  \
    __builtin_amdgcn_global_load_lds(                                        \
        (const __attribute__((address_space(1))) unsigned int*)(gsrc),       \
        (__attribute__((address_space(3))) unsigned int*)(ldst), 16, 0, 0)

// ---------------------------------------------------------------------------
// Setup kernel: one launch does convT16(Ww), convT16(W1w) and prep.
// grid = 64 + 16 + 16 = 96 blocks, 256 threads.
// ---------------------------------------------------------------------------
__device__ __forceinline__ void convT_dev(
    const float* __restrict__ src, ushort* __restrict__ dst,
    int K, int N, int blk, float* tile /* 64*65 floats */)
{
    const int nb = N >> 6;
    const int k0 = (blk / nb) * 64;
    const int n0 = (blk % nb) * 64;
    const int t = threadIdx.x;
    #pragma unroll
    for (int i = 0; i < 16; ++i) {
        int e = i * 256 + t;
        int kr = e >> 6, nc = e & 63;
        tile[nc * 65 + kr] = src[(size_t)(k0 + kr) * N + n0 + nc];
    }
    __syncthreads();
    #pragma unroll
    for (int i = 0; i < 16; ++i) {
        int e = i * 256 + t;
        int nc = e >> 6, kr = e & 63;
        union { _Float16 h; ushort u; } cv;
        cv.h = (_Float16)tile[nc * 65 + kr];
        dst[(size_t)(n0 + nc) * K + k0 + kr] = cv.u;
    }
}

__global__ __launch_bounds__(256) void setup_kernel(
    const float* __restrict__ Ww,  ushort* __restrict__ WwT,
    const float* __restrict__ W1w, ushort* __restrict__ W1T,
    const float* __restrict__ cx, const float* __restrict__ gx,
    const float* __restrict__ Wc, const float* __restrict__ bc,
    const float* __restrict__ Wg, const float* __restrict__ bg,
    const float* __restrict__ W1, const float* __restrict__ b1,
    float* __restrict__ base_out)
{
    __shared__ float smem[64 * 65];
    const int blk = blockIdx.x;
    if (blk < 64) {
        convT_dev(Ww, WwT, W_, WQ_, blk, smem);
        return;
    }
    if (blk < 80) {
        convT_dev(W1w, W1T, H_, H_, blk - 64, smem);
        return;
    }
    // prep: base[b] = c@W1c + g@W1g + b1
    const int b = blk - 80;
    const int t = threadIdx.x;
    float* cxl = smem;              // 64
    float* gxl = smem + 64;         // 256
    float* cl  = smem + 320;        // 64
    float* gl  = smem + 384;        // 256

    if (t < C_) cxl[t] = cx[b * C_ + t];
    gxl[t] = gx[b * G_ + t];
    __syncthreads();

    if (t < C_) {
        float acc = bc[t];
        #pragma unroll 4
        for (int i = 0; i < C_; ++i) acc += cxl[i] * Wc[i * C_ + t];
        cl[t] = acc;
    }
    {
        float acc = bg[t];
        #pragma unroll 4
        for (int i = 0; i < G_; ++i) acc += gxl[i] * Wg[i * G_ + t];
        gl[t] = acc;
    }
    __syncthreads();

    float acc = b1[t];
    #pragma unroll 4
    for (int i = 0; i < C_; ++i) acc += cl[i] * W1[i * H_ + t];
    #pragma unroll 4
    for (int i = 0; i < G_; ++i) acc += gl[i] * W1[(C_ + i) * H_ + t];
    base_out[b * H_ + t] = acc;
}

// ---------------------------------------------------------------------------
// FUSED w GEMM + scores (NO __threadfence — R10's regression was the device
// fence invalidating per-XCD L2s, not the stage-2 L2 reads).
// Stage 1 (== R11 gemm_w): BM=128, BN=256(all), BK=64, 512 thr, 8 waves.
//   B staged via global_load_lds (linear dest, pre-swizzled source); A
//   reg-staged fp32->fp16. w written to global fp16.
// Stage 2: scores for the same 128 rows. w16 read back L2-direct (own
//   stores, first-touch lines; __syncthreads drains vmcnt so stores are in
//   L2), W1T read L2-direct (written by setup_kernel, prior launch).
// grid = M/128 = 512
// ---------------------------------------------------------------------------
__global__ __launch_bounds__(512, 2) void gemm_w_fused(
    const float* __restrict__ A,      // wx  M x 1024 fp32
    const ushort* __restrict__ BT,    // WwT fp16 [256][1024]
    const float* __restrict__ bw,
    const ushort* __restrict__ W1T,   // W1wT fp16 [256 h][256 q]
    const float* __restrict__ base_,  // B_ x 256
    const float* __restrict__ W2,     // 256
    const float* __restrict__ b2,     // 1
    ushort* Cout,                     // w  M x 256 fp16 (written then re-read)
    float* __restrict__ scores)       // M
{
    __shared__ __align__(16) ushort Ah[128 * 64];   // 16 KB, 128B rows
    __shared__ __align__(16) ushort Bh[256 * 64];   // 32 KB, 128B rows
    __shared__ float red2[4][128];                  // 2 KB
    const int t = threadIdx.x;
    const int row0 = blockIdx.x * 128;
    const int b = blockIdx.x >> 5;                  // 32 blocks per batch
    const int lane = t & 63, wave = t >> 6;
    const int wm = wave >> 2, wn = wave & 3;        // 2M x 4N waves
    const int l15 = lane & 15, lq = lane >> 4;

    const int s_ar = t >> 2;            // A row 0..127
    const int s_ak = (t & 3) * 16;      // A k chunk start (16 floats)

    // B staging precompute: linear dest, pre-swizzled source (128B rows)
    const ushort *srcB0, *srcB1, *srcB2, *srcB3;
    char *dstB0, *dstB1, *dstB2, *dstB3;
    {
        const int o0 = t * 16, o1 = o0 + 8192, o2 = o0 + 16384, o3 = o0 + 24576;
        const int c0 = o0 >> 7, c1 = o1 >> 7, c2 = o2 >> 7, c3 = o3 >> 7;
        const int x0 = o0 & 127, x1 = o1 & 127, x2 = o2 & 127, x3 = o3 & 127;
        srcB0 = BT + (size_t)c0 * W_ + ((x0 ^ ((c0 & 7) << 4)) >> 1);
        srcB1 = BT + (size_t)c1 * W_ + ((x1 ^ ((c1 & 7) << 4)) >> 1);
        srcB2 = BT + (size_t)c2 * W_ + ((x2 ^ ((c2 & 7) << 4)) >> 1);
        srcB3 = BT + (size_t)c3 * W_ + ((x3 ^ ((c3 & 7) << 4)) >> 1);
        dstB0 = (char*)Bh + o0; dstB1 = (char*)Bh + o1;
        dstB2 = (char*)Bh + o2; dstB3 = (char*)Bh + o3;
    }

    f32x4 acc[4][4];
    #pragma unroll
    for (int m = 0; m < 4; ++m)
        #pragma unroll
        for (int n = 0; n < 4; ++n) acc[m][n] = (f32x4){0.f, 0.f, 0.f, 0.f};

    // ---------------- stage 1: w = wx @ Ww + bw ----------------
    for (int k0 = 0; k0 < W_; k0 += 64) {
        if (k0) __syncthreads();
        GLOAD16(srcB0 + k0, dstB0);
        GLOAD16(srcB1 + k0, dstB1);
        GLOAD16(srcB2 + k0, dstB2);
        GLOAD16(srcB3 + k0, dstB3);
        {
            const float* ap = A + (size_t)(row0 + s_ar) * W_ + k0 + s_ak;
            const float4 v0 = *(const float4*)(ap + 0);
            const float4 v1 = *(const float4*)(ap + 4);
            const float4 v2 = *(const float4*)(ap + 8);
            const float4 v3 = *(const float4*)(ap + 12);
            f16x8 h0, h1;
            h0[0] = (_Float16)v0.x; h0[1] = (_Float16)v0.y;
            h0[2] = (_Float16)v0.z; h0[3] = (_Float16)v0.w;
            h0[4] = (_Float16)v1.x; h0[5] = (_Float16)v1.y;
            h0[6] = (_Float16)v1.z; h0[7] = (_Float16)v1.w;
            h1[0] = (_Float16)v2.x; h1[1] = (_Float16)v2.y;
            h1[2] = (_Float16)v2.z; h1[3] = (_Float16)v2.w;
            h1[4] = (_Float16)v3.x; h1[5] = (_Float16)v3.y;
            h1[6] = (_Float16)v3.z; h1[7] = (_Float16)v3.w;
            const int base = s_ar * 128 + s_ak * 2;
            const int swz  = (s_ar & 7) << 4;
            *(f16x8*)((char*)Ah + (base ^ swz)) = h0;
            *(f16x8*)((char*)Ah + ((base + 16) ^ swz)) = h1;
        }
        __syncthreads();

        #pragma unroll
        for (int ks = 0; ks < 2; ++ks) {
            f16x8 af[4], bf[4];
            #pragma unroll
            for (int m = 0; m < 4; ++m) {
                const int r = wm * 64 + m * 16 + l15;
                const int byte = (r * 128 + ks * 64 + lq * 16) ^ ((r & 7) << 4);
                af[m] = *(const f16x8*)((const char*)Ah + byte);
            }
            #pragma unroll
            for (int n = 0; n < 4; ++n) {
                const int c = wn * 64 + n * 16 + l15;
                const int byte = (c * 128 + ks * 64 + lq * 16) ^ ((c & 7) << 4);
                bf[n] = *(const f16x8*)((const char*)Bh + byte);
            }
            #pragma unroll
            for (int m = 0; m < 4; ++m)
                #pragma unroll
                for (int n = 0; n < 4; ++n)
                    acc[m][n] = __builtin_amdgcn_mfma_f32_16x16x32_f16(
                        af[m], bf[n], acc[m][n], 0, 0, 0);
        }
    }

    // epilogue 1: w16 -> global
    {
        float bwv[4];
        #pragma unroll
        for (int n = 0; n < 4; ++n) bwv[n] = bw[wn * 64 + n * 16 + l15];
        #pragma unroll
        for (int m = 0; m < 4; ++m)
            #pragma unroll
            for (int reg = 0; reg < 4; ++reg) {
                const size_t r = (size_t)row0 + wm * 64 + m * 16 + lq * 4 + reg;
                #pragma unroll
                for (int n = 0; n < 4; ++n) {
                    union { _Float16 h; ushort u; } cv;
                    cv.h = (_Float16)(acc[m][n][reg] + bwv[n]);
                    Cout[r * WQ_ + wn * 64 + n * 16 + l15] = cv.u;
                }
            }
    }

    // barrier drains vmcnt -> all blocks' OWN stores are in L2; the lines are
    // first-touch for reads, so no stale-L1 hazard. NO __threadfence.
    __syncthreads();

    // ---------------- stage 2: scores = relu(base + w @ W1w) · W2 + b2 ------
    f32x4 acc2[4][4];
    #pragma unroll
    for (int m = 0; m < 4; ++m)
        #pragma unroll
        for (int n = 0; n < 4; ++n) acc2[m][n] = (f32x4){0.f, 0.f, 0.f, 0.f};

    for (int k2 = 0; k2 < WQ_; k2 += 32) {
        f16x8 af[4], bf[4];
        #pragma unroll
        for (int m = 0; m < 4; ++m) {
            const size_t r = (size_t)row0 + wm * 64 + m * 16 + l15;
            af[m] = *(const f16x8*)(Cout + r * WQ_ + k2 + lq * 8);
        }
        #pragma unroll
        for (int n = 0; n < 4; ++n) {
            const int c = wn * 64 + n * 16 + l15;
            bf[n] = *(const f16x8*)(W1T + (size_t)c * WQ_ + k2 + lq * 8);
        }
        #pragma unroll
        for (int m = 0; m < 4; ++m)
            #pragma unroll
            for (int n = 0; n < 4; ++n)
                acc2[m][n] = __builtin_amdgcn_mfma_f32_16x16x32_f16(
                    af[m], bf[n], acc2[m][n], 0, 0, 0);
    }

    // epilogue 2: reduce relu(acc2+base)·W2 over h
    {
        float basev[4], w2v[4];
        #pragma unroll
        for (int n = 0; n < 4; ++n) {
            const int col = wn * 64 + n * 16 + l15;
            basev[n] = base_[b * H_ + col];
            w2v[n] = W2[col];
        }
        #pragma unroll
        for (int m = 0; m < 4; ++m)
            #pragma unroll
            for (int reg = 0; reg < 4; ++reg) {
                float s = 0.f;
                #pragma unroll
                for (int n = 0; n < 4; ++n) {
                    float h = acc2[m][n][reg] + basev[n];
                    h = fmaxf(h, 0.f);
                    s += h * w2v[n];
                }
                s += __shfl_xor(s, 1, 64);
                s += __shfl_xor(s, 2, 64);
                s += __shfl_xor(s, 4, 64);
                s += __shfl_xor(s, 8, 64);
                if (l15 == 0) red2[wn][wm * 64 + m * 16 + lq * 4 + reg] = s;
            }
        __syncthreads();
        if (t < 128) {
            scores[row0 + t] =
                red2[0][t] + red2[1][t] + red2[2][t] + red2[3][t] + b2[0];
        }
    }
}

// ---------------------------------------------------------------------------
// Kernel 3: weighted partial sums; m computed LOCALLY (identical reduction
// code to finalize -> bitwise-identical m, deterministic).
// grid = B_*32, 256 threads.
// ---------------------------------------------------------------------------
__global__ __launch_bounds__(256) void weighted_partial_kernel(
    const ushort* __restrict__ wmat16, const float* __restrict__ scores,
    float* __restrict__ part)
{
    const int blk = blockIdx.x;
    const int b   = blk >> 5;
    const int sl  = blk & 31;
    const int t   = threadIdx.x;
    const int rg  = t >> 5;            // 0..7
    const int q8  = (t & 31) * 8;      // 0..248
    __shared__ float red[8][WQ_];
    __shared__ float mred[4];

    // local max over this batch's scores (L2-hot, 16KB)
    float mv = -1e30f;
    for (int p = t; p < P_; p += 256) mv = fmaxf(mv, scores[b * P_ + p]);
    #pragma unroll
    for (int d = 1; d < 64; d <<= 1) mv = fmaxf(mv, __shfl_xor(mv, d, 64));
    if ((t & 63) == 0) mred[t >> 6] = mv;
    __syncthreads();
    const float m = fmaxf(fmaxf(mred[0], mred[1]), fmaxf(mred[2], mred[3]));

    float acc[8];
    #pragma unroll
    for (int j = 0; j < 8; ++j) acc[j] = 0.f;

    const int p0 = sl * 128 + rg * 16;
    for (int p = p0; p < p0 + 16; ++p) {
        const float e = expf(scores[b * P_ + p] - m);
        const uint4 raw = *(const uint4*)(wmat16 + ((size_t)b * P_ + p) * WQ_ + q8);
        const ushort* u = (const ushort*)&raw;
        #pragma unroll
        for (int j = 0; j < 8; ++j) acc[j] += e * h2f(u[j]);
    }
    #pragma unroll
    for (int j = 0; j < 8; ++j) red[rg][q8 + j] = acc[j];
    __syncthreads();
    float s = 0.f;
    #pragma unroll
    for (int g = 0; g < 8; ++g) s += red[g][t];
    part[(size_t)(b * 32 + sl) * WQ_ + t] = s;
}

// ---------------------------------------------------------------------------
// Kernel 4: finalize — recomputes m (same code as wp -> same value) and z,
// then out = (sum part) / z.  grid = B_, 256 threads.
// ---------------------------------------------------------------------------
__global__ __launch_bounds__(256) void finalize_kernel(
    const float* __restrict__ part, const float* __restrict__ scores,
    float* __restrict__ out)
{
    const int b = blockIdx.x;
    const int t = threadIdx.x;
    __shared__ float mred[4];
    __shared__ float zred[4];

    float mv = -1e30f;
    for (int p = t; p < P_; p += 256) mv = fmaxf(mv, scores[b * P_ + p]);
    #pragma unroll
    for (int d = 1; d < 64; d <<= 1) mv = fmaxf(mv, __shfl_xor(mv, d, 64));
    if ((t & 63) == 0) mred[t >> 6] = mv;
    __syncthreads();
    const float m = fmaxf(fmaxf(mred[0], mred[1]), fmaxf(mred[2], mred[3]));

    float zv = 0.f;
    for (int p = t; p < P_; p += 256) zv += expf(scores[b * P_ + p] - m);
    #pragma unroll
    for (int d = 1; d < 64; d <<= 1) zv += __shfl_xor(zv, d, 64);
    if ((t & 63) == 0) zred[t >> 6] = zv;
    __syncthreads();
    const float z = zred[0] + zred[1] + zred[2] + zred[3];

    float acc = 0.f;
    #pragma unroll
    for (int sl = 0; sl < 32; ++sl) acc += part[(size_t)(b * 32 + sl) * WQ_ + t];
    out[b * WQ_ + t] = acc / z;
}

// ---------------------------------------------------------------------------
extern "C" void kernel_launch(void* const* d_in, const int* in_sizes, int n_in,
                              void* d_out, int out_size, void* d_ws, size_t ws_size,
                              hipStream_t stream) {
    const float* cx = (const float*)d_in[0];
    const float* gx = (const float*)d_in[1];
    const float* wx = (const float*)d_in[2];
    const float* Wc = (const float*)d_in[3];
    const float* bc = (const float*)d_in[4];
    const float* Wg = (const float*)d_in[5];
    const float* bg = (const float*)d_in[6];
    const float* Ww = (const float*)d_in[7];
    const float* bw = (const float*)d_in[8];
    const float* W1 = (const float*)d_in[9];
    const float* b1 = (const float*)d_in[10];
    const float* W2 = (const float*)d_in[11];
    const float* b2 = (const float*)d_in[12];
    float* out = (float*)d_out;

    // workspace layout
    float* ws        = (float*)d_ws;
    ushort* ws_w16   = (ushort*)ws;                      // M_*WQ_ fp16 (32 MB)
    float* ws_scores = ws + (size_t)M_ * WQ_ / 2;        // M_
    float* ws_base   = ws_scores + M_;                   // B_*H_
    float* ws_part   = ws_base + B_ * H_;                // B_*32*WQ_
    ushort* WwT16    = (ushort*)(ws_part + B_ * 32 * WQ_);   // W_*WQ_ fp16
    ushort* W1T16    = WwT16 + (size_t)W_ * WQ_;             // H_*H_ fp16

    setup_kernel<<<96, 256, 0, stream>>>(
        Ww, WwT16, W1 + (size_t)(C_ + G_) * H_, W1T16,
        cx, gx, Wc, bc, Wg, bg, W1, b1, ws_base);

    gemm_w_fused<<<M_ / 128, 512, 0, stream>>>(
        wx, WwT16, bw, W1T16, ws_base, W2, b2, ws_w16, ws_scores);

    weighted_partial_kernel<<<B_ * 32, 256, 0, stream>>>(ws_w16, ws_scores, ws_part);

    finalize_kernel<<<B_, 256, 0, stream>>>(ws_part, ws_scores, out);
}

// Round 13
// 177.164 us; speedup vs baseline: 1.0439x; 1.0439x over previous
//
#include <hip/hip_runtime.h>
#include <hip/hip_bf16.h>

// Problem constants
#define B_   16
#define C_   64
#define G_   256
#define P_   4096
#define W_   1024
#define H_   256
#define WQ_  256
#define M_   (B_ * P_)   // 65536 flattened (b,p) rows

typedef __attribute__((ext_vector_type(8))) _Float16 f16x8;  // MFMA A/B frag
typedef __attribute__((ext_vector_type(4))) float    f32x4;  // MFMA C/D frag

__device__ __forceinline__ float h2f(ushort u) {
    union { ushort u; _Float16 h; } cv; cv.u = u;
    return (float)cv.h;
}

// async global->LDS, 16B per lane (dest = wave-uniform base + lane*16)
#define GLOAD16(gsrc, ldst)                                                  \
    __builtin_amdgcn_global_load_lds(                                        \
        (const __attribute__((address_space(1))) unsigned int*)(gsrc),       \
        (__attribute__((address_space(3))) unsigned int*)(ldst), 16, 0, 0)

// ---------------------------------------------------------------------------
// Setup kernel: convT16(Ww), convT16(W1w), prep — one launch, 96 blocks.
// ---------------------------------------------------------------------------
__device__ __forceinline__ void convT_dev(
    const float* __restrict__ src, ushort* __restrict__ dst,
    int K, int N, int blk, float* tile /* 64*65 floats */)
{
    const int nb = N >> 6;
    const int k0 = (blk / nb) * 64;
    const int n0 = (blk % nb) * 64;
    const int t = threadIdx.x;
    #pragma unroll
    for (int i = 0; i < 16; ++i) {
        int e = i * 256 + t;
        int kr = e >> 6, nc = e & 63;
        tile[nc * 65 + kr] = src[(size_t)(k0 + kr) * N + n0 + nc];
    }
    __syncthreads();
    #pragma unroll
    for (int i = 0; i < 16; ++i) {
        int e = i * 256 + t;
        int nc = e >> 6, kr = e & 63;
        union { _Float16 h; ushort u; } cv;
        cv.h = (_Float16)tile[nc * 65 + kr];
        dst[(size_t)(n0 + nc) * K + k0 + kr] = cv.u;
    }
}

__global__ __launch_bounds__(256) void setup_kernel(
    const float* __restrict__ Ww,  ushort* __restrict__ WwT,
    const float* __restrict__ W1w, ushort* __restrict__ W1T,
    const float* __restrict__ cx, const float* __restrict__ gx,
    const float* __restrict__ Wc, const float* __restrict__ bc,
    const float* __restrict__ Wg, const float* __restrict__ bg,
    const float* __restrict__ W1, const float* __restrict__ b1,
    float* __restrict__ base_out)
{
    __shared__ float smem[64 * 65];
    const int blk = blockIdx.x;
    if (blk < 64) {
        convT_dev(Ww, WwT, W_, WQ_, blk, smem);
        return;
    }
    if (blk < 80) {
        convT_dev(W1w, W1T, H_, H_, blk - 64, smem);
        return;
    }
    const int b = blk - 80;
    const int t = threadIdx.x;
    float* cxl = smem;
    float* gxl = smem + 64;
    float* cl  = smem + 320;
    float* gl  = smem + 384;

    if (t < C_) cxl[t] = cx[b * C_ + t];
    gxl[t] = gx[b * G_ + t];
    __syncthreads();

    if (t < C_) {
        float acc = bc[t];
        #pragma unroll 4
        for (int i = 0; i < C_; ++i) acc += cxl[i] * Wc[i * C_ + t];
        cl[t] = acc;
    }
    {
        float acc = bg[t];
        #pragma unroll 4
        for (int i = 0; i < G_; ++i) acc += gxl[i] * Wg[i * G_ + t];
        gl[t] = acc;
    }
    __syncthreads();

    float acc = b1[t];
    #pragma unroll 4
    for (int i = 0; i < C_; ++i) acc += cl[i] * W1[i * H_ + t];
    #pragma unroll 4
    for (int i = 0; i < G_; ++i) acc += gl[i] * W1[(C_ + i) * H_ + t];
    base_out[b * H_ + t] = acc;
}

// ---------------------------------------------------------------------------
// FUSED w GEMM + scores.
// Stage 1: BM=128, BN=256(all), BK=64, 512 thr, 8 waves (2Mx4N).
//   BOTH operands staged via global_load_lds (A raw fp32, B fp16); linear LDS
//   dests, inverse-swizzled sources (rule #21). fp32->fp16 conversion at
//   FRAGMENT READ (8 v_cvt per frag, co-issues with MFMA — m114). No VGPR
//   staging roundtrip at all.
// Stage 2: w-tile kept in LDS (64KB union over stage-1 buffers); A-frags from
//   swizzled LDS, B (W1T) L2-direct. NO __threadfence (R10 lesson).
// LDS: 64 KB static union -> 2 blocks/CU.
// grid = M/128 = 512
// ---------------------------------------------------------------------------
__global__ __launch_bounds__(512, 2) void gemm_w_fused(
    const float* __restrict__ A,      // wx  M x 1024 fp32
    const ushort* __restrict__ BT,    // WwT fp16 [256][1024]
    const float* __restrict__ bw,
    const ushort* __restrict__ W1T,   // W1wT fp16 [256 h][256 q]
    const float* __restrict__ base_,  // B_ x 256
    const float* __restrict__ W2,     // 256
    const float* __restrict__ b2,     // 1
    ushort* Cout,                     // w  M x 256 fp16
    float* __restrict__ scores)       // M
{
    __shared__ __align__(16) char smem[65536];
    float*  Af = (float*)smem;               // stage1 A: [128][64] f32, 256B rows
    ushort* Bh = (ushort*)(smem + 32768);    // stage1 B: [256][64] f16, 128B rows
    ushort* wt = (ushort*)smem;              // stage2 w: [128][256] f16, 512B rows

    const int t = threadIdx.x;
    const int row0 = blockIdx.x * 128;
    const int b = blockIdx.x >> 5;
    const int lane = t & 63, wave = t >> 6;
    const int wm = wave >> 2, wn = wave & 3;
    const int l15 = lane & 15, lq = lane >> 4;

    // A staging: linear dest o (256B rows), source pre-inverse-swizzled
    const float *srcA0, *srcA1, *srcA2, *srcA3;
    char *dstA0, *dstA1, *dstA2, *dstA3;
    {
        const int o0 = t * 16, o1 = o0 + 8192, o2 = o0 + 16384, o3 = o0 + 24576;
        const int r0 = o0 >> 8, r1 = o1 >> 8, r2 = o2 >> 8, r3 = o3 >> 8;
        srcA0 = A + (size_t)(row0 + r0) * W_ + (((o0 & 255) ^ ((r0 & 7) << 4)) >> 2);
        srcA1 = A + (size_t)(row0 + r1) * W_ + (((o1 & 255) ^ ((r1 & 7) << 4)) >> 2);
        srcA2 = A + (size_t)(row0 + r2) * W_ + (((o2 & 255) ^ ((r2 & 7) << 4)) >> 2);
        srcA3 = A + (size_t)(row0 + r3) * W_ + (((o3 & 255) ^ ((r3 & 7) << 4)) >> 2);
        dstA0 = (char*)Af + o0; dstA1 = (char*)Af + o1;
        dstA2 = (char*)Af + o2; dstA3 = (char*)Af + o3;
    }
    // B staging: linear dest o (128B rows), source pre-inverse-swizzled
    const ushort *srcB0, *srcB1, *srcB2, *srcB3;
    char *dstB0, *dstB1, *dstB2, *dstB3;
    {
        const int o0 = t * 16, o1 = o0 + 8192, o2 = o0 + 16384, o3 = o0 + 24576;
        const int c0 = o0 >> 7, c1 = o1 >> 7, c2 = o2 >> 7, c3 = o3 >> 7;
        srcB0 = BT + (size_t)c0 * W_ + (((o0 & 127) ^ ((c0 & 7) << 4)) >> 1);
        srcB1 = BT + (size_t)c1 * W_ + (((o1 & 127) ^ ((c1 & 7) << 4)) >> 1);
        srcB2 = BT + (size_t)c2 * W_ + (((o2 & 127) ^ ((c2 & 7) << 4)) >> 1);
        srcB3 = BT + (size_t)c3 * W_ + (((o3 & 127) ^ ((c3 & 7) << 4)) >> 1);
        dstB0 = (char*)Bh + o0; dstB1 = (char*)Bh + o1;
        dstB2 = (char*)Bh + o2; dstB3 = (char*)Bh + o3;
    }

    f32x4 acc[4][4];
    #pragma unroll
    for (int m = 0; m < 4; ++m)
        #pragma unroll
        for (int n = 0; n < 4; ++n) acc[m][n] = (f32x4){0.f, 0.f, 0.f, 0.f};

    // ---------------- stage 1: w = wx @ Ww + bw ----------------
    for (int k0 = 0; k0 < W_; k0 += 64) {
        if (k0) __syncthreads();
        GLOAD16(srcA0 + k0, dstA0);
        GLOAD16(srcA1 + k0, dstA1);
        GLOAD16(srcA2 + k0, dstA2);
        GLOAD16(srcA3 + k0, dstA3);
        GLOAD16(srcB0 + k0, dstB0);
        GLOAD16(srcB1 + k0, dstB1);
        GLOAD16(srcB2 + k0, dstB2);
        GLOAD16(srcB3 + k0, dstB3);
        __syncthreads();

        #pragma unroll
        for (int ks = 0; ks < 2; ++ks) {
            f16x8 af[4], bf[4];
            #pragma unroll
            for (int m = 0; m < 4; ++m) {
                const int r = wm * 64 + m * 16 + l15;
                const int base = r * 256 + ks * 128 + lq * 32;
                const int swz  = (r & 7) << 4;
                const f32x4 a0 = *(const f32x4*)((const char*)Af + (base ^ swz));
                const f32x4 a1 = *(const f32x4*)((const char*)Af + ((base + 16) ^ swz));
                f16x8 h;
                h[0] = (_Float16)a0[0]; h[1] = (_Float16)a0[1];
                h[2] = (_Float16)a0[2]; h[3] = (_Float16)a0[3];
                h[4] = (_Float16)a1[0]; h[5] = (_Float16)a1[1];
                h[6] = (_Float16)a1[2]; h[7] = (_Float16)a1[3];
                af[m] = h;
            }
            #pragma unroll
            for (int n = 0; n < 4; ++n) {
                const int c = wn * 64 + n * 16 + l15;
                const int byte = (c * 128 + ks * 64 + lq * 16) ^ ((c & 7) << 4);
                bf[n] = *(const f16x8*)((const char*)Bh + byte);
            }
            #pragma unroll
            for (int m = 0; m < 4; ++m)
                #pragma unroll
                for (int n = 0; n < 4; ++n)
                    acc[m][n] = __builtin_amdgcn_mfma_f32_16x16x32_f16(
                        af[m], bf[n], acc[m][n], 0, 0, 0);
        }
    }

    // epilogue 1: w16 -> global AND swizzled LDS (union over stage-1 buffers)
    __syncthreads();   // stage-1 LDS reads complete before overwrite
    {
        float bwv[4];
        #pragma unroll
        for (int n = 0; n < 4; ++n) bwv[n] = bw[wn * 64 + n * 16 + l15];
        #pragma unroll
        for (int m = 0; m < 4; ++m)
            #pragma unroll
            for (int reg = 0; reg < 4; ++reg) {
                const int rl = wm * 64 + m * 16 + lq * 4 + reg;
                #pragma unroll
                for (int n = 0; n < 4; ++n) {
                    const int col = wn * 64 + n * 16 + l15;
                    union { _Float16 h; ushort u; } cv;
                    cv.h = (_Float16)(acc[m][n][reg] + bwv[n]);
                    Cout[(size_t)(row0 + rl) * WQ_ + col] = cv.u;
                    *(ushort*)((char*)wt + ((rl * 512 + col * 2) ^ ((rl & 7) << 4))) = cv.u;
                }
            }
    }
    __syncthreads();   // w-tile fully written

    // ---------------- stage 2: scores = relu(base + w @ W1w) · W2 + b2 ------
    f32x4 acc2[4][4];
    #pragma unroll
    for (int m = 0; m < 4; ++m)
        #pragma unroll
        for (int n = 0; n < 4; ++n) acc2[m][n] = (f32x4){0.f, 0.f, 0.f, 0.f};

    for (int k2 = 0; k2 < WQ_; k2 += 32) {
        f16x8 af[4], bf[4];
        #pragma unroll
        for (int m = 0; m < 4; ++m) {
            const int r = wm * 64 + m * 16 + l15;
            const int byte = (r * 512 + (k2 + lq * 8) * 2) ^ ((r & 7) << 4);
            af[m] = *(const f16x8*)((const char*)wt + byte);
        }
        #pragma unroll
        for (int n = 0; n < 4; ++n) {
            const int c = wn * 64 + n * 16 + l15;
            bf[n] = *(const f16x8*)(W1T + (size_t)c * WQ_ + k2 + lq * 8);
        }
        #pragma unroll
        for (int m = 0; m < 4; ++m)
            #pragma unroll
            for (int n = 0; n < 4; ++n)
                acc2[m][n] = __builtin_amdgcn_mfma_f32_16x16x32_f16(
                    af[m], bf[n], acc2[m][n], 0, 0, 0);
    }

    __syncthreads();   // all w-tile reads done before red2 aliases smem
    {
        float (*red2)[128] = (float(*)[128])smem;
        float basev[4], w2v[4];
        #pragma unroll
        for (int n = 0; n < 4; ++n) {
            const int col = wn * 64 + n * 16 + l15;
            basev[n] = base_[b * H_ + col];
            w2v[n] = W2[col];
        }
        #pragma unroll
        for (int m = 0; m < 4; ++m)
            #pragma unroll
            for (int reg = 0; reg < 4; ++reg) {
                float s = 0.f;
                #pragma unroll
                for (int n = 0; n < 4; ++n) {
                    float h = acc2[m][n][reg] + basev[n];
                    h = fmaxf(h, 0.f);
                    s += h * w2v[n];
                }
                s += __shfl_xor(s, 1, 64);
                s += __shfl_xor(s, 2, 64);
                s += __shfl_xor(s, 4, 64);
                s += __shfl_xor(s, 8, 64);
                if (l15 == 0) red2[wn][wm * 64 + m * 16 + lq * 4 + reg] = s;
            }
        __syncthreads();
        if (t < 128) {
            scores[row0 + t] =
                red2[0][t] + red2[1][t] + red2[2][t] + red2[3][t] + b2[0];
        }
    }
}

// ---------------------------------------------------------------------------
// Kernel 3: weighted partial sums; m computed locally (identical reduction
// code to finalize -> bitwise-identical m). grid = B_*32, 256 threads.
// ---------------------------------------------------------------------------
__global__ __launch_bounds__(256) void weighted_partial_kernel(
    const ushort* __restrict__ wmat16, const float* __restrict__ scores,
    float* __restrict__ part)
{
    const int blk = blockIdx.x;
    const int b   = blk >> 5;
    const int sl  = blk & 31;
    const int t   = threadIdx.x;
    const int rg  = t >> 5;
    const int q8  = (t & 31) * 8;
    __shared__ float red[8][WQ_];
    __shared__ float mred[4];

    float mv = -1e30f;
    for (int p = t; p < P_; p += 256) mv = fmaxf(mv, scores[b * P_ + p]);
    #pragma unroll
    for (int d = 1; d < 64; d <<= 1) mv = fmaxf(mv, __shfl_xor(mv, d, 64));
    if ((t & 63) == 0) mred[t >> 6] = mv;
    __syncthreads();
    const float m = fmaxf(fmaxf(mred[0], mred[1]), fmaxf(mred[2], mred[3]));

    float acc[8];
    #pragma unroll
    for (int j = 0; j < 8; ++j) acc[j] = 0.f;

    const int p0 = sl * 128 + rg * 16;
    for (int p = p0; p < p0 + 16; ++p) {
        const float e = expf(scores[b * P_ + p] - m);
        const uint4 raw = *(const uint4*)(wmat16 + ((size_t)b * P_ + p) * WQ_ + q8);
        const ushort* u = (const ushort*)&raw;
        #pragma unroll
        for (int j = 0; j < 8; ++j) acc[j] += e * h2f(u[j]);
    }
    #pragma unroll
    for (int j = 0; j < 8; ++j) red[rg][q8 + j] = acc[j];
    __syncthreads();
    float s = 0.f;
    #pragma unroll
    for (int g = 0; g < 8; ++g) s += red[g][t];
    part[(size_t)(b * 32 + sl) * WQ_ + t] = s;
}

// ---------------------------------------------------------------------------
// Kernel 4: finalize — recompute m (same code) and z, out = sum(part)/z.
// ---------------------------------------------------------------------------
__global__ __launch_bounds__(256) void finalize_kernel(
    const float* __restrict__ part, const float* __restrict__ scores,
    float* __restrict__ out)
{
    const int b = blockIdx.x;
    const int t = threadIdx.x;
    __shared__ float mred[4];
    __shared__ float zred[4];

    float mv = -1e30f;
    for (int p = t; p < P_; p += 256) mv = fmaxf(mv, scores[b * P_ + p]);
    #pragma unroll
    for (int d = 1; d < 64; d <<= 1) mv = fmaxf(mv, __shfl_xor(mv, d, 64));
    if ((t & 63) == 0) mred[t >> 6] = mv;
    __syncthreads();
    const float m = fmaxf(fmaxf(mred[0], mred[1]), fmaxf(mred[2], mred[3]));

    float zv = 0.f;
    for (int p = t; p < P_; p += 256) zv += expf(scores[b * P_ + p] - m);
    #pragma unroll
    for (int d = 1; d < 64; d <<= 1) zv += __shfl_xor(zv, d, 64);
    if ((t & 63) == 0) zred[t >> 6] = zv;
    __syncthreads();
    const float z = zred[0] + zred[1] + zred[2] + zred[3];

    float acc = 0.f;
    #pragma unroll
    for (int sl = 0; sl < 32; ++sl) acc += part[(size_t)(b * 32 + sl) * WQ_ + t];
    out[b * WQ_ + t] = acc / z;
}

// ---------------------------------------------------------------------------
extern "C" void kernel_launch(void* const* d_in, const int* in_sizes, int n_in,
                              void* d_out, int out_size, void* d_ws, size_t ws_size,
                              hipStream_t stream) {
    const float* cx = (const float*)d_in[0];
    const float* gx = (const float*)d_in[1];
    const float* wx = (const float*)d_in[2];
    const float* Wc = (const float*)d_in[3];
    const float* bc = (const float*)d_in[4];
    const float* Wg = (const float*)d_in[5];
    const float* bg = (const float*)d_in[6];
    const float* Ww = (const float*)d_in[7];
    const float* bw = (const float*)d_in[8];
    const float* W1 = (const float*)d_in[9];
    const float* b1 = (const float*)d_in[10];
    const float* W2 = (const float*)d_in[11];
    const float* b2 = (const float*)d_in[12];
    float* out = (float*)d_out;

    // workspace layout
    float* ws        = (float*)d_ws;
    ushort* ws_w16   = (ushort*)ws;                      // M_*WQ_ fp16 (32 MB)
    float* ws_scores = ws + (size_t)M_ * WQ_ / 2;        // M_
    float* ws_base   = ws_scores + M_;                   // B_*H_
    float* ws_part   = ws_base + B_ * H_;                // B_*32*WQ_
    ushort* WwT16    = (ushort*)(ws_part + B_ * 32 * WQ_);   // W_*WQ_ fp16
    ushort* W1T16    = WwT16 + (size_t)W_ * WQ_;             // H_*H_ fp16

    setup_kernel<<<96, 256, 0, stream>>>(
        Ww, WwT16, W1 + (size_t)(C_ + G_) * H_, W1T16,
        cx, gx, Wc, bc, Wg, bg, W1, b1, ws_base);

    gemm_w_fused<<<M_ / 128, 512, 0, stream>>>(
        wx, WwT16, bw, W1T16, ws_base, W2, b2, ws_w16, ws_scores);

    weighted_partial_kernel<<<B_ * 32, 256, 0, stream>>>(ws_w16, ws_scores, ws_part);

    finalize_kernel<<<B_, 256, 0, stream>>>(ws_part, ws_scores, out);
}